// Round 13
// baseline (545.618 us; speedup 1.0000x reference)
//
#include <hip/hip_runtime.h>
#include <math.h>

// GAT forward. R13: edge-phase T13 defer-rescale (THR=4) + KV interleaved
// rows (one 512B gather region per edge instead of two 256B ones).
// R12 edge profile: 119us, FETCH 401MB @3.5TB/s AND VALUBusy 70% — at the
// corner of gather-bound and VALU-bound; this attacks both.
// Structure: CSR build -> W pack -> fc0(fp16) -> 2x [ gemm_proj(K,Q,V,ws;
// K/V interleaved) -> fused edge ] -> gemm_fc (fc1+gelu+fc2 fused).

typedef _Float16 f16x8 __attribute__((ext_vector_type(8)));
typedef _Float16 h2 __attribute__((ext_vector_type(2)));
typedef float f32x4 __attribute__((ext_vector_type(4)));

__device__ __forceinline__ ushort f2h(float x) {
    union { _Float16 h; ushort u; } v;
    v.h = (_Float16)x;
    return v.u;
}

// gelu tanh-approx; tanh via e^{2y}: gelu = x * t / (t + 1), t = exp(2y)
__device__ __forceinline__ float gelu_f(float x) {
    float y = 0.7978845608028654f * (x + 0.044715f * x * x * x);
    float t = __expf(2.f * y);
    return x * t / (t + 1.f);
}

__device__ __forceinline__ h2 pk2(float a, float b) {
    return __builtin_bit_cast(h2, __builtin_amdgcn_cvt_pkrtz(a, b));
}

// ---------------- CSR build ----------------
__global__ void k_zero(int* __restrict__ p, int n) {
    int i = blockIdx.x * blockDim.x + threadIdx.x;
    if (i < n) p[i] = 0;
}

__global__ void k_hist(const int* __restrict__ dst, int* __restrict__ deg,
                       int* __restrict__ rank, int e) {
    int i = blockIdx.x * blockDim.x + threadIdx.x;
    if (i < e) rank[i] = atomicAdd(&deg[dst[i]], 1);
}

__global__ __launch_bounds__(256) void k_part(const int* __restrict__ deg,
                                              int* __restrict__ pre,
                                              int* __restrict__ bsum, int n) {
    __shared__ int lds[256];
    int t = threadIdx.x;
    int base = blockIdx.x * 1024 + t * 4;
    int d0 = 0, d1 = 0, d2 = 0, d3 = 0;
    if (base + 3 < n) {
        int4 d = *(const int4*)&deg[base];
        d0 = d.x; d1 = d.y; d2 = d.z; d3 = d.w;
    } else {
        if (base + 0 < n) d0 = deg[base + 0];
        if (base + 1 < n) d1 = deg[base + 1];
        if (base + 2 < n) d2 = deg[base + 2];
        if (base + 3 < n) d3 = deg[base + 3];
    }
    int s0 = d0, s1 = s0 + d1, s2 = s1 + d2, s3 = s2 + d3;
    lds[t] = s3;
    __syncthreads();
    for (int off = 1; off < 256; off <<= 1) {
        int v = (t >= off) ? lds[t - off] : 0;
        __syncthreads();
        lds[t] += v;
        __syncthreads();
    }
    int excl = lds[t] - s3;
    if (base + 0 < n) pre[base + 0] = excl;
    if (base + 1 < n) pre[base + 1] = excl + s0;
    if (base + 2 < n) pre[base + 2] = excl + s1;
    if (base + 3 < n) pre[base + 3] = excl + s2;
    if (t == 255) bsum[blockIdx.x] = lds[255];
}

__global__ void k_scanb(int* __restrict__ bsum, int nb) {
    __shared__ int lds[128];
    int t = threadIdx.x;
    int v = (t < nb) ? bsum[t] : 0;
    lds[t] = v;
    __syncthreads();
    for (int off = 1; off < 128; off <<= 1) {
        int u = (t >= off) ? lds[t - off] : 0;
        __syncthreads();
        lds[t] += u;
        __syncthreads();
    }
    if (t < nb) bsum[t] = lds[t] - v;
}

__global__ __launch_bounds__(256) void k_add(int* __restrict__ rowp,
                                             const int* __restrict__ bsum, int n,
                                             int e) {
    int t = threadIdx.x;
    int base = blockIdx.x * 1024 + t * 4;
    int off = bsum[blockIdx.x];
#pragma unroll
    for (int j = 0; j < 4; ++j) {
        int i = base + j;
        if (i < n) rowp[i] += off;
    }
    if (blockIdx.x == 0 && t == 0) rowp[n] = e;
}

__global__ void k_scatter(const int* __restrict__ src, const int* __restrict__ dst,
                          const int* __restrict__ rank, const int* __restrict__ rowp,
                          int* __restrict__ csrc, int e) {
    int i = blockIdx.x * blockDim.x + threadIdx.x;
    if (i < e) csrc[rowp[dst[i]] + rank[i]] = src[i];
}

// ---------------- W pack: fp32 [128][128] -> fp16 frag-major ----------------
__global__ void k_pack(const float* __restrict__ Wk, const float* __restrict__ Wq,
                       const float* __restrict__ Wv, const float* __restrict__ Ws,
                       const float* __restrict__ Wfc1, ushort* __restrict__ Wp) {
    int id = blockIdx.y;
    const float* src;
    if (id < 8) {
        int m = id & 3, layer = id >> 2;
        src = (m == 0) ? Wk : (m == 1) ? Wq : (m == 2) ? Wv : Ws;
        src += layer * 16384;
    } else {
        src = Wfc1;
    }
    int o = blockIdx.x * 256 + threadIdx.x;
    int j = o & 7, l = (o >> 3) & 63, nf = (o >> 9) & 7, kc = o >> 12;
    int row = kc * 32 + ((l >> 4) << 3) + j;
    int col = nf * 16 + (l & 15);
    Wp[id * 16384 + o] = f2h(src[row * 128 + col]);
}

// ---------------- fc0: [N,16] @ [16,128] + b -> fp16 ----------------
__global__ __launch_bounds__(256) void k_fc0(const float* __restrict__ X,
                                             const float* __restrict__ W,
                                             const float* __restrict__ b,
                                             ushort* __restrict__ H, int n) {
    __shared__ float Ws[16 * 128];
    __shared__ float xs[2][16];
    int t = threadIdx.x;
#pragma unroll
    for (int i = 0; i < 8; ++i) Ws[t + i * 256] = W[t + i * 256];
    if (t < 32) {
        int nn = blockIdx.x * 2 + (t >> 4);
        xs[t >> 4][t & 15] = (nn < n) ? X[nn * 16 + (t & 15)] : 0.f;
    }
    __syncthreads();
    int nd = blockIdx.x * 2 + (t >> 7);
    if (nd < n) {
        int c = t & 127;
        float acc = b[c];
#pragma unroll
        for (int j = 0; j < 16; ++j) acc += xs[t >> 7][j] * Ws[j * 128 + c];
        H[(size_t)nd * 128 + c] = f2h(acc);
    }
}

// ---- A staging: fp16 global -> fp16 LDS [64][128], XOR-swizzled ----
__device__ __forceinline__ void stage_Ah(const ushort* __restrict__ A, int n,
                                         int rbase, char* Asb, int t) {
#pragma unroll
    for (int i = 0; i < 4; ++i) {
        int b = t * 16 + i * 4096;  // byte offset in tile (row-major, 256B rows)
        int r = b >> 8;
        uint4 v = {0u, 0u, 0u, 0u};
        if (rbase + r < n)
            v = *(const uint4*)((const char*)A + (size_t)rbase * 256 + b);
        *(uint4*)(Asb + (b ^ ((r & 7) << 4))) = v;
    }
}

// ---------------- proj GEMM: [N,128] @ [128,128] x 4, fp16 out --------------
// Per-output ushort row stride (ostr) supports the interleaved KV layout.
// Epilogue: C -> As (swizzled fp16) -> full-wave streaming stores.
__global__ __launch_bounds__(256) void k_gemm_proj(
    const ushort* __restrict__ A, int n, const ushort* __restrict__ Wp,
    const float* __restrict__ b0, ushort* __restrict__ o0, int ostr0,
    const float* __restrict__ b1, ushort* __restrict__ o1, int ostr1,
    const float* __restrict__ b2_, ushort* __restrict__ o2, int ostr2,
    const float* __restrict__ b3, ushort* __restrict__ o3, int ostr3) {
    __shared__ ushort As[64 * 128];   // 16 KB: A tile, then C staging
    __shared__ ushort Ws[16384];      // 32 KB: one W matrix
    char* Asb = (char*)As;
    int t = threadIdx.x;
    int rbase = blockIdx.x * 64;

    stage_Ah(A, n, rbase, Asb, t);

    // prefetch W_0 (one matrix = 2048 uint4)
    const uint4* wsrc = (const uint4*)Wp;
    uint4 wreg[8];
#pragma unroll
    for (int i = 0; i < 8; ++i) wreg[i] = wsrc[t + i * 256];

    __syncthreads();  // As ready

    int w = t >> 6, l = t & 63;
    int arow = w * 16 + (l & 15);
    int kq = l >> 4;

    f16x8 a[4];
#pragma unroll
    for (int kc = 0; kc < 4; ++kc) {
        int byte = (arow * 256 + kc * 64 + kq * 16) ^ ((arow & 7) << 4);
        a[kc] = *(const f16x8*)(Asb + byte);
    }
    __syncthreads();  // everyone has a[] before As is reused for C staging

    for (int m = 0; m < 4; ++m) {
        // write prefetched W_m -> Ws
#pragma unroll
        for (int i = 0; i < 8; ++i) ((uint4*)Ws)[t + i * 256] = wreg[i];
        __syncthreads();  // Ws ready; prev C-flush reads of As also done

        if (m < 3) {
#pragma unroll
            for (int i = 0; i < 8; ++i)
                wreg[i] = wsrc[(m + 1) * 2048 + t + i * 256];
        }

        const float* bias; ushort* op; int ostr;
        if (m == 0)      { bias = b0; op = o0; ostr = ostr0; }
        else if (m == 1) { bias = b1; op = o1; ostr = ostr1; }
        else if (m == 2) { bias = b2_; op = o2; ostr = ostr2; }
        else             { bias = b3; op = o3; ostr = ostr3; }

        f32x4 acc[8];
#pragma unroll
        for (int nf = 0; nf < 8; ++nf) acc[nf] = (f32x4){0.f, 0.f, 0.f, 0.f};

#pragma unroll
        for (int kc = 0; kc < 4; ++kc) {
#pragma unroll
            for (int nf = 0; nf < 8; ++nf) {
                f16x8 b = *(const f16x8*)(Ws + (((kc * 8 + nf) * 64 + l) << 3));
                acc[nf] = __builtin_amdgcn_mfma_f32_16x16x32_f16(a[kc], b, acc[nf], 0, 0, 0);
            }
        }
        __syncthreads();  // Ws reads done; As free

        // C -> As (swizzled fp16, +bias)
#pragma unroll
        for (int nf = 0; nf < 8; ++nf) {
            int col = nf * 16 + (l & 15);
            float bia = bias[col];
#pragma unroll
            for (int r = 0; r < 4; ++r) {
                int row = w * 16 + (l >> 4) * 4 + r;
                int b = (row * 256 + col * 2) ^ ((row & 7) << 4);
                *(ushort*)(Asb + b) = f2h(acc[nf][r] + bia);
            }
        }
        __syncthreads();  // C staged

        // coalesced flush: 4 x 16B per thread (ostr = dest row stride, ushorts)
#pragma unroll
        for (int i = 0; i < 4; ++i) {
            int b = t * 16 + i * 4096;
            int r = b >> 8, c = b & 255;  // c = byte col within 256B tile row
            uint4 v = *(const uint4*)(Asb + (b ^ ((r & 7) << 4)));
            if (rbase + r < n)
                *(uint4*)((char*)op + (size_t)(rbase + r) * ostr * 2 + c) = v;
        }
        // next iteration's Ws-write + sync fences these As reads
    }
}

// ---------------- fc GEMM: fc1 (gelu) + fc2 fused -> out [N,4] ----------------
__global__ __launch_bounds__(256) void k_gemm_fc(
    const ushort* __restrict__ A, int n, const ushort* __restrict__ Wp,
    const float* __restrict__ bias1, const float* __restrict__ W2,
    const float* __restrict__ bias2, float* __restrict__ out2) {
    __shared__ ushort As[64 * 128];
    __shared__ ushort Ws[16384];
    char* Asb = (char*)As;
    int t = threadIdx.x;
    int rbase = blockIdx.x * 64;

    stage_Ah(A, n, rbase, Asb, t);

    const uint4* wsrc = (const uint4*)Wp;
#pragma unroll
    for (int i = 0; i < 8; ++i) ((uint4*)Ws)[t + i * 256] = wsrc[t + i * 256];

    __syncthreads();

    int w = t >> 6, l = t & 63;
    int arow = w * 16 + (l & 15);
    int kq = l >> 4;

    f16x8 a[4];
#pragma unroll
    for (int kc = 0; kc < 4; ++kc) {
        int byte = (arow * 256 + kc * 64 + kq * 16) ^ ((arow & 7) << 4);
        a[kc] = *(const f16x8*)(Asb + byte);
    }

    f32x4 acc[8];
#pragma unroll
    for (int nf = 0; nf < 8; ++nf) acc[nf] = (f32x4){0.f, 0.f, 0.f, 0.f};

#pragma unroll
    for (int kc = 0; kc < 4; ++kc) {
#pragma unroll
        for (int nf = 0; nf < 8; ++nf) {
            f16x8 b = *(const f16x8*)(Ws + (((kc * 8 + nf) * 64 + l) << 3));
            acc[nf] = __builtin_amdgcn_mfma_f32_16x16x32_f16(a[kc], b, acc[nf], 0, 0, 0);
        }
    }

    // fc1 gelu + fc2 [128x4] fused epilogue
    float pj[4][4];
#pragma unroll
    for (int r = 0; r < 4; ++r)
#pragma unroll
        for (int j = 0; j < 4; ++j) pj[r][j] = 0.f;
#pragma unroll
    for (int nf = 0; nf < 8; ++nf) {
        int col = nf * 16 + (l & 15);
        float4 w2v = *(const float4*)&W2[col * 4];
        float bia = bias1[col];
#pragma unroll
        for (int r = 0; r < 4; ++r) {
            float o = gelu_f(acc[nf][r] + bia);
            pj[r][0] += o * w2v.x;
            pj[r][1] += o * w2v.y;
            pj[r][2] += o * w2v.z;
            pj[r][3] += o * w2v.w;
        }
    }
#pragma unroll
    for (int off = 1; off < 16; off <<= 1)
#pragma unroll
        for (int r = 0; r < 4; ++r)
#pragma unroll
            for (int j = 0; j < 4; ++j)
                pj[r][j] += __shfl_xor(pj[r][j], off);
    int jj = l & 15;
    if (jj < 4) {
#pragma unroll
        for (int r = 0; r < 4; ++r) {
            int row = rbase + w * 16 + (l >> 4) * 4 + r;
            if (row < n) {
                float v = (jj == 0) ? pj[r][0] : (jj == 1) ? pj[r][1]
                        : (jj == 2) ? pj[r][2] : pj[r][3];
                out2[(size_t)row * 4 + jj] = v + bias2[jj];
            }
        }
    }
}

// ---------------- fused edge phase: one wave/dst node, 4 edges/iter --------
// KV interleaved: row s = [K(128 fp16) | V(128 fp16)] = 512B contiguous.
// T13 defer-rescale: m only updates when sc > m + 4 (subgroup-uniform rare
// branch); p <= e^4 keeps fp16 PV accum far from overflow.
__global__ void k_edge_hf(const ushort* __restrict__ KV, const ushort* __restrict__ Q,
                          const int* __restrict__ rowp, const int* __restrict__ csrc,
                          ushort* __restrict__ H, int n, int act) {
    int wid = (int)((blockIdx.x * blockDim.x + threadIdx.x) >> 6);
    int lane = threadIdx.x & 63;
    if (wid >= n) return;
    int qb = lane >> 4;                 // edge slot within quad
    unsigned fb = (lane & 15) * 8u;     // feature base
    int e0 = rowp[wid], e1 = rowp[wid + 1];

    uint4 qr = *(const uint4*)(Q + (((unsigned)wid << 7) + fb));
    h2 q0 = __builtin_bit_cast(h2, qr.x), q1 = __builtin_bit_cast(h2, qr.y);
    h2 q2 = __builtin_bit_cast(h2, qr.z), q3 = __builtin_bit_cast(h2, qr.w);

    float m = -1e30f, denom = 0.f;
    h2 hz = {(_Float16)0.f, (_Float16)0.f};
    h2 acc0 = hz, acc1 = hz, acc2 = hz, acc3 = hz;

    for (int eb = e0; eb < e1; eb += 64) {
        int cnt = min(64, e1 - eb);
        int sl = (eb + lane < e1) ? csrc[eb + lane] : 0;
        int full = cnt >> 2;
#pragma unroll 2
        for (int j = 0; j < full; ++j) {
            int s = __shfl(sl, 4 * j + qb);
            unsigned off = ((unsigned)s << 8) + fb;
            uint4 kr = *(const uint4*)(KV + off);
            float sc = __builtin_amdgcn_fdot2(__builtin_bit_cast(h2, kr.x), q0,
                       __builtin_amdgcn_fdot2(__builtin_bit_cast(h2, kr.y), q1,
                       __builtin_amdgcn_fdot2(__builtin_bit_cast(h2, kr.z), q2,
                       __builtin_amdgcn_fdot2(__builtin_bit_cast(h2, kr.w), q3,
                                              0.f, false), false), false), false);
            sc += __shfl_xor(sc, 1);
            sc += __shfl_xor(sc, 2);
            sc += __shfl_xor(sc, 4);
            uint4 vr = *(const uint4*)(KV + off + 128);
            if (sc > m + 4.f) {          // rare: rescale to new max
                float ss = __expf(m - sc);
                m = sc;
                denom *= ss;
                h2 hs = pk2(ss, ss);
                acc0 *= hs; acc1 *= hs; acc2 *= hs; acc3 *= hs;
            }
            float p = __expf(sc - m);    // <= e^4
            denom += p;
            h2 hp = pk2(p, p);
            acc0 = __builtin_bit_cast(h2, vr.x) * hp + acc0;
            acc1 = __builtin_bit_cast(h2, vr.y) * hp + acc1;
            acc2 = __builtin_bit_cast(h2, vr.z) * hp + acc2;
            acc3 = __builtin_bit_cast(h2, vr.w) * hp + acc3;
        }
        int rem = cnt & 3;
        if (rem) {
            bool val = qb < rem;
            int s = __shfl(sl, full * 4 + qb);
            unsigned off = ((unsigned)s << 8) + fb;
            uint4 kr = *(const uint4*)(KV + off);
            float sc = __builtin_amdgcn_fdot2(__builtin_bit_cast(h2, kr.x), q0,
                       __builtin_amdgcn_fdot2(__builtin_bit_cast(h2, kr.y), q1,
                       __builtin_amdgcn_fdot2(__builtin_bit_cast(h2, kr.z), q2,
                       __builtin_amdgcn_fdot2(__builtin_bit_cast(h2, kr.w), q3,
                                              0.f, false), false), false), false);
            sc += __shfl_xor(sc, 1);
            sc += __shfl_xor(sc, 2);
            sc += __shfl_xor(sc, 4);
            uint4 vr = *(const uint4*)(KV + off + 128);
            if (val && sc > m + 4.f) {
                float ss = __expf(m - sc);
                m = sc;
                denom *= ss;
                h2 hs = pk2(ss, ss);
                acc0 *= hs; acc1 *= hs; acc2 *= hs; acc3 *= hs;
            }
            float p = val ? __expf(sc - m) : 0.f;
            denom += p;
            h2 hp = pk2(p, p);
            acc0 = __builtin_bit_cast(h2, vr.x) * hp + acc0;
            acc1 = __builtin_bit_cast(h2, vr.y) * hp + acc1;
            acc2 = __builtin_bit_cast(h2, vr.z) * hp + acc2;
            acc3 = __builtin_bit_cast(h2, vr.w) * hp + acc3;
        }
    }

    // merge quarter states: lanes L, L^16, L^32, L^48 share (feats, head)
#pragma unroll
    for (int dist = 16; dist <= 32; dist <<= 1) {
        float mo = __shfl_xor(m, dist);
        float dn = __shfl_xor(denom, dist);
        unsigned w0 = __shfl_xor(__builtin_bit_cast(unsigned, acc0), dist);
        unsigned w1 = __shfl_xor(__builtin_bit_cast(unsigned, acc1), dist);
        unsigned w2 = __shfl_xor(__builtin_bit_cast(unsigned, acc2), dist);
        unsigned w3 = __shfl_xor(__builtin_bit_cast(unsigned, acc3), dist);
        float mn = fmaxf(m, mo);
        float sA = __expf(m - mn), sB = __expf(mo - mn);
        denom = denom * sA + dn * sB;
        h2 hA = pk2(sA, sA), hB = pk2(sB, sB);
        acc0 = acc0 * hA + __builtin_bit_cast(h2, w0) * hB;
        acc1 = acc1 * hA + __builtin_bit_cast(h2, w1) * hB;
        acc2 = acc2 * hA + __builtin_bit_cast(h2, w2) * hB;
        acc3 = acc3 * hA + __builtin_bit_cast(h2, w3) * hB;
        m = mn;
    }

    if (lane < 16) {
        float inv = (denom > 0.f) ? 1.f / denom : 0.f;
        ushort* hp = H + (((unsigned)wid << 7) + fb);
        uint4 hr = *(const uint4*)hp;
        h2 s0 = __builtin_bit_cast(h2, hr.x), s1 = __builtin_bit_cast(h2, hr.y);
        h2 s2 = __builtin_bit_cast(h2, hr.z), s3 = __builtin_bit_cast(h2, hr.w);
        float o0 = (float)s0.x + (float)acc0.x * inv;
        float o1 = (float)s0.y + (float)acc0.y * inv;
        float o2 = (float)s1.x + (float)acc1.x * inv;
        float o3 = (float)s1.y + (float)acc1.y * inv;
        float o4 = (float)s2.x + (float)acc2.x * inv;
        float o5 = (float)s2.y + (float)acc2.y * inv;
        float o6 = (float)s3.x + (float)acc3.x * inv;
        float o7 = (float)s3.y + (float)acc3.y * inv;
        if (act) {
            o0 = gelu_f(o0); o1 = gelu_f(o1); o2 = gelu_f(o2); o3 = gelu_f(o3);
            o4 = gelu_f(o4); o5 = gelu_f(o5); o6 = gelu_f(o6); o7 = gelu_f(o7);
        }
        uint4 o;
        o.x = __builtin_bit_cast(unsigned, pk2(o0, o1));
        o.y = __builtin_bit_cast(unsigned, pk2(o2, o3));
        o.z = __builtin_bit_cast(unsigned, pk2(o4, o5));
        o.w = __builtin_bit_cast(unsigned, pk2(o6, o7));
        *(uint4*)hp = o;
    }
}

extern "C" void kernel_launch(void* const* d_in, const int* in_sizes, int n_in,
                              void* d_out, int out_size, void* d_ws, size_t ws_size,
                              hipStream_t stream) {
    const float* x     = (const float*)d_in[0];
    const int*   src   = (const int*)d_in[1];
    const int*   dst   = (const int*)d_in[2];
    const float* fc0_w = (const float*)d_in[3];
    const float* fc0_b = (const float*)d_in[4];
    const float* Wk    = (const float*)d_in[5];
    const float* bk    = (const float*)d_in[6];
    const float* Wq    = (const float*)d_in[7];
    const float* bq    = (const float*)d_in[8];
    const float* Wv    = (const float*)d_in[9];
    const float* bv    = (const float*)d_in[10];
    const float* ws_w  = (const float*)d_in[11];
    const float* ws_b  = (const float*)d_in[12];
    const float* fc1_w = (const float*)d_in[13];
    const float* fc1_b = (const float*)d_in[14];
    const float* fc2_w = (const float*)d_in[15];
    const float* fc2_b = (const float*)d_in[16];

    int n = in_sizes[0] / 16;
    int e = in_sizes[1];

    ushort* hA  = (ushort*)d_ws;
    ushort* hB  = hA + (size_t)n * 128;
    ushort* KV  = hB + (size_t)n * 128;   // [n][256]: K | V interleaved
    ushort* Qb  = KV + (size_t)n * 256;
    ushort* Wp  = Qb + (size_t)n * 128;   // 9 * 16384 fp16
    int* deg    = (int*)(Wp + 9 * 16384);
    int* rowp   = deg + n;
    int* csrc   = rowp + n + 1;
    int* rank   = csrc + e;
    int* bsum   = rank + e;               // 128 ints scratch

    int nb = (n + 1023) / 1024;

    // CSR build
    k_zero<<<(n + 255) / 256, 256, 0, stream>>>(deg, n);
    k_hist<<<(e + 255) / 256, 256, 0, stream>>>(dst, deg, rank, e);
    k_part<<<nb, 256, 0, stream>>>(deg, rowp, bsum, n);
    k_scanb<<<1, 128, 0, stream>>>(bsum, nb);
    k_add<<<nb, 256, 0, stream>>>(rowp, bsum, n, e);
    k_scatter<<<(e + 255) / 256, 256, 0, stream>>>(src, dst, rank, rowp, csrc, e);

    // pack all 9 weight matrices to fp16 frag-major
    k_pack<<<dim3(64, 9), 256, 0, stream>>>(Wk, Wq, Wv, ws_w, fc1_w, Wp);

    // fc0 -> fp16 hA
    k_fc0<<<(n + 1) / 2, 256, 0, stream>>>(x, fc0_w, fc0_b, hA, n);

    int gx = (n + 63) / 64;
    // layer 0: K->KV[:,0:128], Q->Qb, V->KV[:,128:256], ws->hB. Then edge.
    k_gemm_proj<<<gx, 256, 0, stream>>>(hA, n, Wp, bk, KV, 256, bq, Qb, 128,
                                        bv, KV + 128, 256, ws_b, hB, 128);
    k_edge_hf<<<(n + 3) / 4, 256, 0, stream>>>(KV, Qb, rowp, csrc, hB, n, 1);
    // layer 1
    k_gemm_proj<<<gx, 256, 0, stream>>>(hB, n, Wp + 4 * 16384, bk + 128, KV, 256,
                                        bq + 128, Qb, 128, bv + 128, KV + 128, 256,
                                        ws_b + 128, hA, 128);
    k_edge_hf<<<(n + 3) / 4, 256, 0, stream>>>(KV, Qb, rowp, csrc, hA, n, 0);

    // fc1 + gelu + fc2 fused -> d_out
    k_gemm_fc<<<gx, 256, 0, stream>>>(hA, n, Wp + 8 * 16384, fc1_b, fc2_w, fc2_b,
                                      (float*)d_out);
}

// Round 14
// 544.778 us; speedup vs baseline: 1.0015x; 1.0015x over previous
//
#include <hip/hip_runtime.h>
#include <math.h>

// GAT forward. R14: edge kernel MLP restructure. R13 showed edge pinned at
// 118us with FETCH 401MB @3.7TB/s (below HBM ceiling), VALU 64%, occ 76% —
// latency-bound on the per-iteration dependent gather chain. Now each
// 64-edge block is processed in chunks of 16 edges: all 8 K/V uint4 loads
// issued back-to-back (8 outstanding/wave), then 4 compute bodies consume.
// Structure: CSR build -> W pack -> fc0(fp16) -> 2x [ gemm_proj(KV ilv) ->
// fused edge ] -> gemm_fc (fc1+gelu+fc2 fused).

typedef _Float16 f16x8 __attribute__((ext_vector_type(8)));
typedef _Float16 h2 __attribute__((ext_vector_type(2)));
typedef float f32x4 __attribute__((ext_vector_type(4)));

__device__ __forceinline__ ushort f2h(float x) {
    union { _Float16 h; ushort u; } v;
    v.h = (_Float16)x;
    return v.u;
}

// gelu tanh-approx; tanh via e^{2y}: gelu = x * t / (t + 1), t = exp(2y)
__device__ __forceinline__ float gelu_f(float x) {
    float y = 0.7978845608028654f * (x + 0.044715f * x * x * x);
    float t = __expf(2.f * y);
    return x * t / (t + 1.f);
}

__device__ __forceinline__ h2 pk2(float a, float b) {
    return __builtin_bit_cast(h2, __builtin_amdgcn_cvt_pkrtz(a, b));
}

// ---------------- CSR build ----------------
__global__ void k_zero(int* __restrict__ p, int n) {
    int i = blockIdx.x * blockDim.x + threadIdx.x;
    if (i < n) p[i] = 0;
}

__global__ void k_hist(const int* __restrict__ dst, int* __restrict__ deg,
                       int* __restrict__ rank, int e) {
    int i = blockIdx.x * blockDim.x + threadIdx.x;
    if (i < e) rank[i] = atomicAdd(&deg[dst[i]], 1);
}

__global__ __launch_bounds__(256) void k_part(const int* __restrict__ deg,
                                              int* __restrict__ pre,
                                              int* __restrict__ bsum, int n) {
    __shared__ int lds[256];
    int t = threadIdx.x;
    int base = blockIdx.x * 1024 + t * 4;
    int d0 = 0, d1 = 0, d2 = 0, d3 = 0;
    if (base + 3 < n) {
        int4 d = *(const int4*)&deg[base];
        d0 = d.x; d1 = d.y; d2 = d.z; d3 = d.w;
    } else {
        if (base + 0 < n) d0 = deg[base + 0];
        if (base + 1 < n) d1 = deg[base + 1];
        if (base + 2 < n) d2 = deg[base + 2];
        if (base + 3 < n) d3 = deg[base + 3];
    }
    int s0 = d0, s1 = s0 + d1, s2 = s1 + d2, s3 = s2 + d3;
    lds[t] = s3;
    __syncthreads();
    for (int off = 1; off < 256; off <<= 1) {
        int v = (t >= off) ? lds[t - off] : 0;
        __syncthreads();
        lds[t] += v;
        __syncthreads();
    }
    int excl = lds[t] - s3;
    if (base + 0 < n) pre[base + 0] = excl;
    if (base + 1 < n) pre[base + 1] = excl + s0;
    if (base + 2 < n) pre[base + 2] = excl + s1;
    if (base + 3 < n) pre[base + 3] = excl + s2;
    if (t == 255) bsum[blockIdx.x] = lds[255];
}

__global__ void k_scanb(int* __restrict__ bsum, int nb) {
    __shared__ int lds[128];
    int t = threadIdx.x;
    int v = (t < nb) ? bsum[t] : 0;
    lds[t] = v;
    __syncthreads();
    for (int off = 1; off < 128; off <<= 1) {
        int u = (t >= off) ? lds[t - off] : 0;
        __syncthreads();
        lds[t] += u;
        __syncthreads();
    }
    if (t < nb) bsum[t] = lds[t] - v;
}

__global__ __launch_bounds__(256) void k_add(int* __restrict__ rowp,
                                             const int* __restrict__ bsum, int n,
                                             int e) {
    int t = threadIdx.x;
    int base = blockIdx.x * 1024 + t * 4;
    int off = bsum[blockIdx.x];
#pragma unroll
    for (int j = 0; j < 4; ++j) {
        int i = base + j;
        if (i < n) rowp[i] += off;
    }
    if (blockIdx.x == 0 && t == 0) rowp[n] = e;
}

__global__ void k_scatter(const int* __restrict__ src, const int* __restrict__ dst,
                          const int* __restrict__ rank, const int* __restrict__ rowp,
                          int* __restrict__ csrc, int e) {
    int i = blockIdx.x * blockDim.x + threadIdx.x;
    if (i < e) csrc[rowp[dst[i]] + rank[i]] = src[i];
}

// ---------------- W pack: fp32 [128][128] -> fp16 frag-major ----------------
__global__ void k_pack(const float* __restrict__ Wk, const float* __restrict__ Wq,
                       const float* __restrict__ Wv, const float* __restrict__ Ws,
                       const float* __restrict__ Wfc1, ushort* __restrict__ Wp) {
    int id = blockIdx.y;
    const float* src;
    if (id < 8) {
        int m = id & 3, layer = id >> 2;
        src = (m == 0) ? Wk : (m == 1) ? Wq : (m == 2) ? Wv : Ws;
        src += layer * 16384;
    } else {
        src = Wfc1;
    }
    int o = blockIdx.x * 256 + threadIdx.x;
    int j = o & 7, l = (o >> 3) & 63, nf = (o >> 9) & 7, kc = o >> 12;
    int row = kc * 32 + ((l >> 4) << 3) + j;
    int col = nf * 16 + (l & 15);
    Wp[id * 16384 + o] = f2h(src[row * 128 + col]);
}

// ---------------- fc0: [N,16] @ [16,128] + b -> fp16 ----------------
__global__ __launch_bounds__(256) void k_fc0(const float* __restrict__ X,
                                             const float* __restrict__ W,
                                             const float* __restrict__ b,
                                             ushort* __restrict__ H, int n) {
    __shared__ float Ws[16 * 128];
    __shared__ float xs[2][16];
    int t = threadIdx.x;
#pragma unroll
    for (int i = 0; i < 8; ++i) Ws[t + i * 256] = W[t + i * 256];
    if (t < 32) {
        int nn = blockIdx.x * 2 + (t >> 4);
        xs[t >> 4][t & 15] = (nn < n) ? X[nn * 16 + (t & 15)] : 0.f;
    }
    __syncthreads();
    int nd = blockIdx.x * 2 + (t >> 7);
    if (nd < n) {
        int c = t & 127;
        float acc = b[c];
#pragma unroll
        for (int j = 0; j < 16; ++j) acc += xs[t >> 7][j] * Ws[j * 128 + c];
        H[(size_t)nd * 128 + c] = f2h(acc);
    }
}

// ---- A staging: fp16 global -> fp16 LDS [64][128], XOR-swizzled ----
__device__ __forceinline__ void stage_Ah(const ushort* __restrict__ A, int n,
                                         int rbase, char* Asb, int t) {
#pragma unroll
    for (int i = 0; i < 4; ++i) {
        int b = t * 16 + i * 4096;  // byte offset in tile (row-major, 256B rows)
        int r = b >> 8;
        uint4 v = {0u, 0u, 0u, 0u};
        if (rbase + r < n)
            v = *(const uint4*)((const char*)A + (size_t)rbase * 256 + b);
        *(uint4*)(Asb + (b ^ ((r & 7) << 4))) = v;
    }
}

// ---------------- proj GEMM: [N,128] @ [128,128] x 4, fp16 out --------------
__global__ __launch_bounds__(256) void k_gemm_proj(
    const ushort* __restrict__ A, int n, const ushort* __restrict__ Wp,
    const float* __restrict__ b0, ushort* __restrict__ o0, int ostr0,
    const float* __restrict__ b1, ushort* __restrict__ o1, int ostr1,
    const float* __restrict__ b2_, ushort* __restrict__ o2, int ostr2,
    const float* __restrict__ b3, ushort* __restrict__ o3, int ostr3) {
    __shared__ ushort As[64 * 128];   // 16 KB: A tile, then C staging
    __shared__ ushort Ws[16384];      // 32 KB: one W matrix
    char* Asb = (char*)As;
    int t = threadIdx.x;
    int rbase = blockIdx.x * 64;

    stage_Ah(A, n, rbase, Asb, t);

    const uint4* wsrc = (const uint4*)Wp;
    uint4 wreg[8];
#pragma unroll
    for (int i = 0; i < 8; ++i) wreg[i] = wsrc[t + i * 256];

    __syncthreads();  // As ready

    int w = t >> 6, l = t & 63;
    int arow = w * 16 + (l & 15);
    int kq = l >> 4;

    f16x8 a[4];
#pragma unroll
    for (int kc = 0; kc < 4; ++kc) {
        int byte = (arow * 256 + kc * 64 + kq * 16) ^ ((arow & 7) << 4);
        a[kc] = *(const f16x8*)(Asb + byte);
    }
    __syncthreads();  // everyone has a[] before As is reused for C staging

    for (int m = 0; m < 4; ++m) {
#pragma unroll
        for (int i = 0; i < 8; ++i) ((uint4*)Ws)[t + i * 256] = wreg[i];
        __syncthreads();  // Ws ready; prev C-flush reads of As also done

        if (m < 3) {
#pragma unroll
            for (int i = 0; i < 8; ++i)
                wreg[i] = wsrc[(m + 1) * 2048 + t + i * 256];
        }

        const float* bias; ushort* op; int ostr;
        if (m == 0)      { bias = b0; op = o0; ostr = ostr0; }
        else if (m == 1) { bias = b1; op = o1; ostr = ostr1; }
        else if (m == 2) { bias = b2_; op = o2; ostr = ostr2; }
        else             { bias = b3; op = o3; ostr = ostr3; }

        f32x4 acc[8];
#pragma unroll
        for (int nf = 0; nf < 8; ++nf) acc[nf] = (f32x4){0.f, 0.f, 0.f, 0.f};

#pragma unroll
        for (int kc = 0; kc < 4; ++kc) {
#pragma unroll
            for (int nf = 0; nf < 8; ++nf) {
                f16x8 b = *(const f16x8*)(Ws + (((kc * 8 + nf) * 64 + l) << 3));
                acc[nf] = __builtin_amdgcn_mfma_f32_16x16x32_f16(a[kc], b, acc[nf], 0, 0, 0);
            }
        }
        __syncthreads();  // Ws reads done; As free

#pragma unroll
        for (int nf = 0; nf < 8; ++nf) {
            int col = nf * 16 + (l & 15);
            float bia = bias[col];
#pragma unroll
            for (int r = 0; r < 4; ++r) {
                int row = w * 16 + (l >> 4) * 4 + r;
                int b = (row * 256 + col * 2) ^ ((row & 7) << 4);
                *(ushort*)(Asb + b) = f2h(acc[nf][r] + bia);
            }
        }
        __syncthreads();  // C staged

#pragma unroll
        for (int i = 0; i < 4; ++i) {
            int b = t * 16 + i * 4096;
            int r = b >> 8, c = b & 255;
            uint4 v = *(const uint4*)(Asb + (b ^ ((r & 7) << 4)));
            if (rbase + r < n)
                *(uint4*)((char*)op + (size_t)(rbase + r) * ostr * 2 + c) = v;
        }
    }
}

// ---------------- fc GEMM: fc1 (gelu) + fc2 fused -> out [N,4] ----------------
__global__ __launch_bounds__(256) void k_gemm_fc(
    const ushort* __restrict__ A, int n, const ushort* __restrict__ Wp,
    const float* __restrict__ bias1, const float* __restrict__ W2,
    const float* __restrict__ bias2, float* __restrict__ out2) {
    __shared__ ushort As[64 * 128];
    __shared__ ushort Ws[16384];
    char* Asb = (char*)As;
    int t = threadIdx.x;
    int rbase = blockIdx.x * 64;

    stage_Ah(A, n, rbase, Asb, t);

    const uint4* wsrc = (const uint4*)Wp;
#pragma unroll
    for (int i = 0; i < 8; ++i) ((uint4*)Ws)[t + i * 256] = wsrc[t + i * 256];

    __syncthreads();

    int w = t >> 6, l = t & 63;
    int arow = w * 16 + (l & 15);
    int kq = l >> 4;

    f16x8 a[4];
#pragma unroll
    for (int kc = 0; kc < 4; ++kc) {
        int byte = (arow * 256 + kc * 64 + kq * 16) ^ ((arow & 7) << 4);
        a[kc] = *(const f16x8*)(Asb + byte);
    }

    f32x4 acc[8];
#pragma unroll
    for (int nf = 0; nf < 8; ++nf) acc[nf] = (f32x4){0.f, 0.f, 0.f, 0.f};

#pragma unroll
    for (int kc = 0; kc < 4; ++kc) {
#pragma unroll
        for (int nf = 0; nf < 8; ++nf) {
            f16x8 b = *(const f16x8*)(Ws + (((kc * 8 + nf) * 64 + l) << 3));
            acc[nf] = __builtin_amdgcn_mfma_f32_16x16x32_f16(a[kc], b, acc[nf], 0, 0, 0);
        }
    }

    float pj[4][4];
#pragma unroll
    for (int r = 0; r < 4; ++r)
#pragma unroll
        for (int j = 0; j < 4; ++j) pj[r][j] = 0.f;
#pragma unroll
    for (int nf = 0; nf < 8; ++nf) {
        int col = nf * 16 + (l & 15);
        float4 w2v = *(const float4*)&W2[col * 4];
        float bia = bias1[col];
#pragma unroll
        for (int r = 0; r < 4; ++r) {
            float o = gelu_f(acc[nf][r] + bia);
            pj[r][0] += o * w2v.x;
            pj[r][1] += o * w2v.y;
            pj[r][2] += o * w2v.z;
            pj[r][3] += o * w2v.w;
        }
    }
#pragma unroll
    for (int off = 1; off < 16; off <<= 1)
#pragma unroll
        for (int r = 0; r < 4; ++r)
#pragma unroll
            for (int j = 0; j < 4; ++j)
                pj[r][j] += __shfl_xor(pj[r][j], off);
    int jj = l & 15;
    if (jj < 4) {
#pragma unroll
        for (int r = 0; r < 4; ++r) {
            int row = rbase + w * 16 + (l >> 4) * 4 + r;
            if (row < n) {
                float v = (jj == 0) ? pj[r][0] : (jj == 1) ? pj[r][1]
                        : (jj == 2) ? pj[r][2] : pj[r][3];
                out2[(size_t)row * 4 + jj] = v + bias2[jj];
            }
        }
    }
}

// ---------------- fused edge phase: one wave/dst node -----------------------
// KV interleaved rows (512B). Chunked MLP: up to 16 edges (4 quad-iters) of
// K/V loads issued back-to-back before compute. T13 defer-rescale (THR=4).
__global__ void k_edge_hf(const ushort* __restrict__ KV, const ushort* __restrict__ Q,
                          const int* __restrict__ rowp, const int* __restrict__ csrc,
                          ushort* __restrict__ H, int n, int act) {
    int wid = (int)((blockIdx.x * blockDim.x + threadIdx.x) >> 6);
    int lane = threadIdx.x & 63;
    if (wid >= n) return;
    int qb = lane >> 4;                 // edge slot within quad
    unsigned fb = (lane & 15) * 8u;     // feature base
    int e0 = rowp[wid], e1 = rowp[wid + 1];

    uint4 qr = *(const uint4*)(Q + (((unsigned)wid << 7) + fb));
    h2 q0 = __builtin_bit_cast(h2, qr.x), q1 = __builtin_bit_cast(h2, qr.y);
    h2 q2 = __builtin_bit_cast(h2, qr.z), q3 = __builtin_bit_cast(h2, qr.w);

    float m = -1e30f, denom = 0.f;
    h2 hz = {(_Float16)0.f, (_Float16)0.f};
    h2 acc0 = hz, acc1 = hz, acc2 = hz, acc3 = hz;

#define EDGE_BODY(KR, VR, VALID)                                               \
    {                                                                          \
        float sc = __builtin_amdgcn_fdot2(__builtin_bit_cast(h2, KR.x), q0,    \
                   __builtin_amdgcn_fdot2(__builtin_bit_cast(h2, KR.y), q1,    \
                   __builtin_amdgcn_fdot2(__builtin_bit_cast(h2, KR.z), q2,    \
                   __builtin_amdgcn_fdot2(__builtin_bit_cast(h2, KR.w), q3,    \
                                          0.f, false), false), false), false); \
        sc += __shfl_xor(sc, 1);                                               \
        sc += __shfl_xor(sc, 2);                                               \
        sc += __shfl_xor(sc, 4);                                               \
        if (VALID && sc > m + 4.f) {                                           \
            float ss = __expf(m - sc);                                         \
            m = sc;                                                            \
            denom *= ss;                                                       \
            h2 hs = pk2(ss, ss);                                               \
            acc0 *= hs; acc1 *= hs; acc2 *= hs; acc3 *= hs;                    \
        }                                                                      \
        float p = VALID ? __expf(sc - m) : 0.f;                                \
        denom += p;                                                            \
        h2 hp = pk2(p, p);                                                     \
        acc0 = __builtin_bit_cast(h2, VR.x) * hp + acc0;                       \
        acc1 = __builtin_bit_cast(h2, VR.y) * hp + acc1;                       \
        acc2 = __builtin_bit_cast(h2, VR.z) * hp + acc2;                       \
        acc3 = __builtin_bit_cast(h2, VR.w) * hp + acc3;                       \
    }

    for (int eb = e0; eb < e1; eb += 64) {
        int cnt = min(64, e1 - eb);
        int sl = (eb + lane < e1) ? csrc[eb + lane] : 0;
        int nq = (cnt + 3) >> 2;  // quad-iterations (<=16)
        for (int c0 = 0; c0 < nq; c0 += 4) {
            // ---- prefetch phase: issue up to 8 loads back-to-back ----
            int ei0 = (c0 + 0) * 4 + qb, ei1 = (c0 + 1) * 4 + qb;
            int ei2 = (c0 + 2) * 4 + qb, ei3 = (c0 + 3) * 4 + qb;
            bool v0 = ei0 < cnt, v1 = ei1 < cnt, v2 = ei2 < cnt, v3 = ei3 < cnt;
            unsigned of0 = (((unsigned)__shfl(sl, ei0 & 63)) << 8) + fb;
            unsigned of1 = (((unsigned)__shfl(sl, ei1 & 63)) << 8) + fb;
            unsigned of2 = (((unsigned)__shfl(sl, ei2 & 63)) << 8) + fb;
            unsigned of3 = (((unsigned)__shfl(sl, ei3 & 63)) << 8) + fb;
            uint4 kr0 = *(const uint4*)(KV + of0);
            uint4 vr0 = *(const uint4*)(KV + of0 + 128);
            uint4 kr1 = *(const uint4*)(KV + of1);
            uint4 vr1 = *(const uint4*)(KV + of1 + 128);
            uint4 kr2 = *(const uint4*)(KV + of2);
            uint4 vr2 = *(const uint4*)(KV + of2 + 128);
            uint4 kr3 = *(const uint4*)(KV + of3);
            uint4 vr3 = *(const uint4*)(KV + of3 + 128);
            // ---- compute phase ----
            EDGE_BODY(kr0, vr0, v0);
            if (v1 || c0 + 4 < nq) EDGE_BODY(kr1, vr1, v1);
            if (v2 || c0 + 4 < nq) EDGE_BODY(kr2, vr2, v2);
            if (v3 || c0 + 4 < nq) EDGE_BODY(kr3, vr3, v3);
        }
    }
#undef EDGE_BODY

    // merge quarter states: lanes L, L^16, L^32, L^48 share (feats, head)
#pragma unroll
    for (int dist = 16; dist <= 32; dist <<= 1) {
        float mo = __shfl_xor(m, dist);
        float dn = __shfl_xor(denom, dist);
        unsigned w0 = __shfl_xor(__builtin_bit_cast(unsigned, acc0), dist);
        unsigned w1 = __shfl_xor(__builtin_bit_cast(unsigned, acc1), dist);
        unsigned w2 = __shfl_xor(__builtin_bit_cast(unsigned, acc2), dist);
        unsigned w3 = __shfl_xor(__builtin_bit_cast(unsigned, acc3), dist);
        float mn = fmaxf(m, mo);
        float sA = __expf(m - mn), sB = __expf(mo - mn);
        denom = denom * sA + dn * sB;
        h2 hA = pk2(sA, sA), hB = pk2(sB, sB);
        acc0 = acc0 * hA + __builtin_bit_cast(h2, w0) * hB;
        acc1 = acc1 * hA + __builtin_bit_cast(h2, w1) * hB;
        acc2 = acc2 * hA + __builtin_bit_cast(h2, w2) * hB;
        acc3 = acc3 * hA + __builtin_bit_cast(h2, w3) * hB;
        m = mn;
    }

    if (lane < 16) {
        float inv = (denom > 0.f) ? 1.f / denom : 0.f;
        ushort* hp = H + (((unsigned)wid << 7) + fb);
        uint4 hr = *(const uint4*)hp;
        h2 s0 = __builtin_bit_cast(h2, hr.x), s1 = __builtin_bit_cast(h2, hr.y);
        h2 s2 = __builtin_bit_cast(h2, hr.z), s3 = __builtin_bit_cast(h2, hr.w);
        float o0 = (float)s0.x + (float)acc0.x * inv;
        float o1 = (float)s0.y + (float)acc0.y * inv;
        float o2 = (float)s1.x + (float)acc1.x * inv;
        float o3 = (float)s1.y + (float)acc1.y * inv;
        float o4 = (float)s2.x + (float)acc2.x * inv;
        float o5 = (float)s2.y + (float)acc2.y * inv;
        float o6 = (float)s3.x + (float)acc3.x * inv;
        float o7 = (float)s3.y + (float)acc3.y * inv;
        if (act) {
            o0 = gelu_f(o0); o1 = gelu_f(o1); o2 = gelu_f(o2); o3 = gelu_f(o3);
            o4 = gelu_f(o4); o5 = gelu_f(o5); o6 = gelu_f(o6); o7 = gelu_f(o7);
        }
        uint4 o;
        o.x = __builtin_bit_cast(unsigned, pk2(o0, o1));
        o.y = __builtin_bit_cast(unsigned, pk2(o2, o3));
        o.z = __builtin_bit_cast(unsigned, pk2(o4, o5));
        o.w = __builtin_bit_cast(unsigned, pk2(o6, o7));
        *(uint4*)hp = o;
    }
}

extern "C" void kernel_launch(void* const* d_in, const int* in_sizes, int n_in,
                              void* d_out, int out_size, void* d_ws, size_t ws_size,
                              hipStream_t stream) {
    const float* x     = (const float*)d_in[0];
    const int*   src   = (const int*)d_in[1];
    const int*   dst   = (const int*)d_in[2];
    const float* fc0_w = (const float*)d_in[3];
    const float* fc0_b = (const float*)d_in[4];
    const float* Wk    = (const float*)d_in[5];
    const float* bk    = (const float*)d_in[6];
    const float* Wq    = (const float*)d_in[7];
    const float* bq    = (const float*)d_in[8];
    const float* Wv    = (const float*)d_in[9];
    const float* bv    = (const float*)d_in[10];
    const float* ws_w  = (const float*)d_in[11];
    const float* ws_b  = (const float*)d_in[12];
    const float* fc1_w = (const float*)d_in[13];
    const float* fc1_b = (const float*)d_in[14];
    const float* fc2_w = (const float*)d_in[15];
    const float* fc2_b = (const float*)d_in[16];

    int n = in_sizes[0] / 16;
    int e = in_sizes[1];

    ushort* hA  = (ushort*)d_ws;
    ushort* hB  = hA + (size_t)n * 128;
    ushort* KV  = hB + (size_t)n * 128;   // [n][256]: K | V interleaved
    ushort* Qb  = KV + (size_t)n * 256;
    ushort* Wp  = Qb + (size_t)n * 128;   // 9 * 16384 fp16
    int* deg    = (int*)(Wp + 9 * 16384);
    int* rowp   = deg + n;
    int* csrc   = rowp + n + 1;
    int* rank   = csrc + e;
    int* bsum   = rank + e;               // 128 ints scratch

    int nb = (n + 1023) / 1024;

    // CSR build
    k_zero<<<(n + 255) / 256, 256, 0, stream>>>(deg, n);
    k_hist<<<(e + 255) / 256, 256, 0, stream>>>(dst, deg, rank, e);
    k_part<<<nb, 256, 0, stream>>>(deg, rowp, bsum, n);
    k_scanb<<<1, 128, 0, stream>>>(bsum, nb);
    k_add<<<nb, 256, 0, stream>>>(rowp, bsum, n, e);
    k_scatter<<<(e + 255) / 256, 256, 0, stream>>>(src, dst, rank, rowp, csrc, e);

    // pack all 9 weight matrices to fp16 frag-major
    k_pack<<<dim3(64, 9), 256, 0, stream>>>(Wk, Wq, Wv, ws_w, fc1_w, Wp);

    // fc0 -> fp16 hA
    k_fc0<<<(n + 1) / 2, 256, 0, stream>>>(x, fc0_w, fc0_b, hA, n);

    int gx = (n + 63) / 64;
    // layer 0: K->KV[:,0:128], Q->Qb, V->KV[:,128:256], ws->hB. Then edge.
    k_gemm_proj<<<gx, 256, 0, stream>>>(hA, n, Wp, bk, KV, 256, bq, Qb, 128,
                                        bv, KV + 128, 256, ws_b, hB, 128);
    k_edge_hf<<<(n + 3) / 4, 256, 0, stream>>>(KV, Qb, rowp, csrc, hB, n, 1);
    // layer 1
    k_gemm_proj<<<gx, 256, 0, stream>>>(hB, n, Wp + 4 * 16384, bk + 128, KV, 256,
                                        bq + 128, Qb, 128, bv + 128, KV + 128, 256,
                                        ws_b + 128, hA, 128);
    k_edge_hf<<<(n + 3) / 4, 256, 0, stream>>>(KV, Qb, rowp, csrc, hA, n, 0);

    // fc1 + gelu + fc2 fused -> d_out
    k_gemm_fc<<<gx, 256, 0, stream>>>(hA, n, Wp + 8 * 16384, fc1_b, fc2_w, fc2_b,
                                      (float*)d_out);
}

// Round 15
// 525.553 us; speedup vs baseline: 1.0382x; 1.0366x over previous
//
#include <hip/hip_runtime.h>
#include <math.h>

// GAT forward. R15: consolidation. Edge kernel declared at its random-gather
// floor (118us; 3 independent levers all neutral; 3.7TB/s L2-fill on 51MB
// working set). This round removes known waste: fc0 fused into proj-L0
// (h0 lives only in LDS), k_zero replaced by hipMemsetAsync.
// Structure: CSR build -> W pack -> 2x [ gemm_proj(+fc0 for L0) -> fused
// edge ] -> gemm_fc (fc1+gelu+fc2 fused).

typedef _Float16 f16x8 __attribute__((ext_vector_type(8)));
typedef _Float16 h2 __attribute__((ext_vector_type(2)));
typedef float f32x4 __attribute__((ext_vector_type(4)));

__device__ __forceinline__ ushort f2h(float x) {
    union { _Float16 h; ushort u; } v;
    v.h = (_Float16)x;
    return v.u;
}

// gelu tanh-approx; tanh via e^{2y}: gelu = x * t / (t + 1), t = exp(2y)
__device__ __forceinline__ float gelu_f(float x) {
    float y = 0.7978845608028654f * (x + 0.044715f * x * x * x);
    float t = __expf(2.f * y);
    return x * t / (t + 1.f);
}

__device__ __forceinline__ h2 pk2(float a, float b) {
    return __builtin_bit_cast(h2, __builtin_amdgcn_cvt_pkrtz(a, b));
}

// ---------------- CSR build ----------------
__global__ void k_hist(const int* __restrict__ dst, int* __restrict__ deg,
                       int* __restrict__ rank, int e) {
    int i = blockIdx.x * blockDim.x + threadIdx.x;
    if (i < e) rank[i] = atomicAdd(&deg[dst[i]], 1);
}

__global__ __launch_bounds__(256) void k_part(const int* __restrict__ deg,
                                              int* __restrict__ pre,
                                              int* __restrict__ bsum, int n) {
    __shared__ int lds[256];
    int t = threadIdx.x;
    int base = blockIdx.x * 1024 + t * 4;
    int d0 = 0, d1 = 0, d2 = 0, d3 = 0;
    if (base + 3 < n) {
        int4 d = *(const int4*)&deg[base];
        d0 = d.x; d1 = d.y; d2 = d.z; d3 = d.w;
    } else {
        if (base + 0 < n) d0 = deg[base + 0];
        if (base + 1 < n) d1 = deg[base + 1];
        if (base + 2 < n) d2 = deg[base + 2];
        if (base + 3 < n) d3 = deg[base + 3];
    }
    int s0 = d0, s1 = s0 + d1, s2 = s1 + d2, s3 = s2 + d3;
    lds[t] = s3;
    __syncthreads();
    for (int off = 1; off < 256; off <<= 1) {
        int v = (t >= off) ? lds[t - off] : 0;
        __syncthreads();
        lds[t] += v;
        __syncthreads();
    }
    int excl = lds[t] - s3;
    if (base + 0 < n) pre[base + 0] = excl;
    if (base + 1 < n) pre[base + 1] = excl + s0;
    if (base + 2 < n) pre[base + 2] = excl + s1;
    if (base + 3 < n) pre[base + 3] = excl + s2;
    if (t == 255) bsum[blockIdx.x] = lds[255];
}

__global__ void k_scanb(int* __restrict__ bsum, int nb) {
    __shared__ int lds[128];
    int t = threadIdx.x;
    int v = (t < nb) ? bsum[t] : 0;
    lds[t] = v;
    __syncthreads();
    for (int off = 1; off < 128; off <<= 1) {
        int u = (t >= off) ? lds[t - off] : 0;
        __syncthreads();
        lds[t] += u;
        __syncthreads();
    }
    if (t < nb) bsum[t] = lds[t] - v;
}

__global__ __launch_bounds__(256) void k_add(int* __restrict__ rowp,
                                             const int* __restrict__ bsum, int n,
                                             int e) {
    int t = threadIdx.x;
    int base = blockIdx.x * 1024 + t * 4;
    int off = bsum[blockIdx.x];
#pragma unroll
    for (int j = 0; j < 4; ++j) {
        int i = base + j;
        if (i < n) rowp[i] += off;
    }
    if (blockIdx.x == 0 && t == 0) rowp[n] = e;
}

__global__ void k_scatter(const int* __restrict__ src, const int* __restrict__ dst,
                          const int* __restrict__ rank, const int* __restrict__ rowp,
                          int* __restrict__ csrc, int e) {
    int i = blockIdx.x * blockDim.x + threadIdx.x;
    if (i < e) csrc[rowp[dst[i]] + rank[i]] = src[i];
}

// ---------------- W pack: fp32 [128][128] -> fp16 frag-major ----------------
__global__ void k_pack(const float* __restrict__ Wk, const float* __restrict__ Wq,
                       const float* __restrict__ Wv, const float* __restrict__ Ws,
                       const float* __restrict__ Wfc1, ushort* __restrict__ Wp) {
    int id = blockIdx.y;
    const float* src;
    if (id < 8) {
        int m = id & 3, layer = id >> 2;
        src = (m == 0) ? Wk : (m == 1) ? Wq : (m == 2) ? Wv : Ws;
        src += layer * 16384;
    } else {
        src = Wfc1;
    }
    int o = blockIdx.x * 256 + threadIdx.x;
    int j = o & 7, l = (o >> 3) & 63, nf = (o >> 9) & 7, kc = o >> 12;
    int row = kc * 32 + ((l >> 4) << 3) + j;
    int col = nf * 16 + (l & 15);
    Wp[id * 16384 + o] = f2h(src[row * 128 + col]);
}

// ---- A staging: fp16 global -> fp16 LDS [64][128], XOR-swizzled ----
__device__ __forceinline__ void stage_Ah(const ushort* __restrict__ A, int n,
                                         int rbase, char* Asb, int t) {
#pragma unroll
    for (int i = 0; i < 4; ++i) {
        int b = t * 16 + i * 4096;  // byte offset in tile (row-major, 256B rows)
        int r = b >> 8;
        uint4 v = {0u, 0u, 0u, 0u};
        if (rbase + r < n)
            v = *(const uint4*)((const char*)A + (size_t)rbase * 256 + b);
        *(uint4*)(Asb + (b ^ ((r & 7) << 4))) = v;
    }
}

// ---------------- proj GEMM: [N,128] @ [128,128] x 4, fp16 out --------------
// fc0mode: A-tile computed in-LDS as h0 = X@W0 + B0 (fc0 fusion, layer 0).
__global__ __launch_bounds__(256) void k_gemm_proj(
    const ushort* __restrict__ A, int n, const ushort* __restrict__ Wp,
    const float* __restrict__ b0, ushort* __restrict__ o0, int ostr0,
    const float* __restrict__ b1, ushort* __restrict__ o1, int ostr1,
    const float* __restrict__ b2_, ushort* __restrict__ o2, int ostr2,
    const float* __restrict__ b3, ushort* __restrict__ o3, int ostr3,
    const float* __restrict__ X0, const float* __restrict__ W0,
    const float* __restrict__ B0, int fc0mode) {
    __shared__ ushort As[64 * 128];   // 16 KB: A tile, then C staging
    __shared__ ushort Ws[16384];      // 32 KB: one W matrix (or fc0 scratch)
    char* Asb = (char*)As;
    int t = threadIdx.x;
    int rbase = blockIdx.x * 64;

    // prefetch W matrix 0 (one matrix = 2048 uint4)
    const uint4* wsrc = (const uint4*)Wp;
    uint4 wreg[8];
#pragma unroll
    for (int i = 0; i < 8; ++i) wreg[i] = wsrc[t + i * 256];

    if (fc0mode) {
        // fc0 fusion: h0 tile = X[64x16] @ W0[16x128] + B0, fp32 accum.
        float* WT  = (float*)Ws;      // [128][16] transposed weights (8 KB)
        float* bi0 = WT + 2048;       // [128] bias
        float* xs  = bi0 + 128;       // [64][16] X tile (4 KB)
#pragma unroll
        for (int i = 0; i < 8; ++i) {
            int idx = t * 8 + i;      // 0..2047
            WT[idx] = W0[(idx & 15) * 128 + (idx >> 4)];
        }
        if (t < 128) bi0[t] = B0[t];
        {
            int row = t >> 2, k0 = (t & 3) * 4;
            float4 xv = {0.f, 0.f, 0.f, 0.f};
            if (rbase + row < n)
                xv = *(const float4*)&X0[(size_t)(rbase + row) * 16 + k0];
            *(float4*)&xs[row * 16 + k0] = xv;
        }
        __syncthreads();
        int row = t >> 2;
        float x[16];
#pragma unroll
        for (int i = 0; i < 4; ++i)
            *(float4*)&x[i * 4] = *(const float4*)&xs[row * 16 + i * 4];
        int cbase = (t & 3) * 32;
        for (int c = cbase; c < cbase + 32; ++c) {
            const float4* wc = (const float4*)&WT[c * 16];
            float4 wa = wc[0], wb = wc[1], wd = wc[2], we = wc[3];
            float acc = bi0[c];
            acc += x[0] * wa.x + x[1] * wa.y + x[2] * wa.z + x[3] * wa.w;
            acc += x[4] * wb.x + x[5] * wb.y + x[6] * wb.z + x[7] * wb.w;
            acc += x[8] * wd.x + x[9] * wd.y + x[10] * wd.z + x[11] * wd.w;
            acc += x[12] * we.x + x[13] * we.y + x[14] * we.z + x[15] * we.w;
            int b = (row * 256 + c * 2) ^ ((row & 7) << 4);
            *(ushort*)(Asb + b) = f2h(acc);
        }
    } else {
        stage_Ah(A, n, rbase, Asb, t);
    }
    __syncthreads();  // As ready

    int w = t >> 6, l = t & 63;
    int arow = w * 16 + (l & 15);
    int kq = l >> 4;

    f16x8 a[4];
#pragma unroll
    for (int kc = 0; kc < 4; ++kc) {
        int byte = (arow * 256 + kc * 64 + kq * 16) ^ ((arow & 7) << 4);
        a[kc] = *(const f16x8*)(Asb + byte);
    }
    __syncthreads();  // everyone has a[] before As is reused for C staging

    for (int m = 0; m < 4; ++m) {
#pragma unroll
        for (int i = 0; i < 8; ++i) ((uint4*)Ws)[t + i * 256] = wreg[i];
        __syncthreads();  // Ws ready; prev C-flush reads of As also done

        if (m < 3) {
#pragma unroll
            for (int i = 0; i < 8; ++i)
                wreg[i] = wsrc[(m + 1) * 2048 + t + i * 256];
        }

        const float* bias; ushort* op; int ostr;
        if (m == 0)      { bias = b0; op = o0; ostr = ostr0; }
        else if (m == 1) { bias = b1; op = o1; ostr = ostr1; }
        else if (m == 2) { bias = b2_; op = o2; ostr = ostr2; }
        else             { bias = b3; op = o3; ostr = ostr3; }

        f32x4 acc[8];
#pragma unroll
        for (int nf = 0; nf < 8; ++nf) acc[nf] = (f32x4){0.f, 0.f, 0.f, 0.f};

#pragma unroll
        for (int kc = 0; kc < 4; ++kc) {
#pragma unroll
            for (int nf = 0; nf < 8; ++nf) {
                f16x8 b = *(const f16x8*)(Ws + (((kc * 8 + nf) * 64 + l) << 3));
                acc[nf] = __builtin_amdgcn_mfma_f32_16x16x32_f16(a[kc], b, acc[nf], 0, 0, 0);
            }
        }
        __syncthreads();  // Ws reads done; As free

#pragma unroll
        for (int nf = 0; nf < 8; ++nf) {
            int col = nf * 16 + (l & 15);
            float bia = bias[col];
#pragma unroll
            for (int r = 0; r < 4; ++r) {
                int row = w * 16 + (l >> 4) * 4 + r;
                int b = (row * 256 + col * 2) ^ ((row & 7) << 4);
                *(ushort*)(Asb + b) = f2h(acc[nf][r] + bia);
            }
        }
        __syncthreads();  // C staged

#pragma unroll
        for (int i = 0; i < 4; ++i) {
            int b = t * 16 + i * 4096;
            int r = b >> 8, c = b & 255;
            uint4 v = *(const uint4*)(Asb + (b ^ ((r & 7) << 4)));
            if (rbase + r < n)
                *(uint4*)((char*)op + (size_t)(rbase + r) * ostr * 2 + c) = v;
        }
    }
}

// ---------------- fc GEMM: fc1 (gelu) + fc2 fused -> out [N,4] ----------------
__global__ __launch_bounds__(256) void k_gemm_fc(
    const ushort* __restrict__ A, int n, const ushort* __restrict__ Wp,
    const float* __restrict__ bias1, const float* __restrict__ W2,
    const float* __restrict__ bias2, float* __restrict__ out2) {
    __shared__ ushort As[64 * 128];
    __shared__ ushort Ws[16384];
    char* Asb = (char*)As;
    int t = threadIdx.x;
    int rbase = blockIdx.x * 64;

    stage_Ah(A, n, rbase, Asb, t);

    const uint4* wsrc = (const uint4*)Wp;
#pragma unroll
    for (int i = 0; i < 8; ++i) ((uint4*)Ws)[t + i * 256] = wsrc[t + i * 256];

    __syncthreads();

    int w = t >> 6, l = t & 63;
    int arow = w * 16 + (l & 15);
    int kq = l >> 4;

    f16x8 a[4];
#pragma unroll
    for (int kc = 0; kc < 4; ++kc) {
        int byte = (arow * 256 + kc * 64 + kq * 16) ^ ((arow & 7) << 4);
        a[kc] = *(const f16x8*)(Asb + byte);
    }

    f32x4 acc[8];
#pragma unroll
    for (int nf = 0; nf < 8; ++nf) acc[nf] = (f32x4){0.f, 0.f, 0.f, 0.f};

#pragma unroll
    for (int kc = 0; kc < 4; ++kc) {
#pragma unroll
        for (int nf = 0; nf < 8; ++nf) {
            f16x8 b = *(const f16x8*)(Ws + (((kc * 8 + nf) * 64 + l) << 3));
            acc[nf] = __builtin_amdgcn_mfma_f32_16x16x32_f16(a[kc], b, acc[nf], 0, 0, 0);
        }
    }

    float pj[4][4];
#pragma unroll
    for (int r = 0; r < 4; ++r)
#pragma unroll
        for (int j = 0; j < 4; ++j) pj[r][j] = 0.f;
#pragma unroll
    for (int nf = 0; nf < 8; ++nf) {
        int col = nf * 16 + (l & 15);
        float4 w2v = *(const float4*)&W2[col * 4];
        float bia = bias1[col];
#pragma unroll
        for (int r = 0; r < 4; ++r) {
            float o = gelu_f(acc[nf][r] + bia);
            pj[r][0] += o * w2v.x;
            pj[r][1] += o * w2v.y;
            pj[r][2] += o * w2v.z;
            pj[r][3] += o * w2v.w;
        }
    }
#pragma unroll
    for (int off = 1; off < 16; off <<= 1)
#pragma unroll
        for (int r = 0; r < 4; ++r)
#pragma unroll
            for (int j = 0; j < 4; ++j)
                pj[r][j] += __shfl_xor(pj[r][j], off);
    int jj = l & 15;
    if (jj < 4) {
#pragma unroll
        for (int r = 0; r < 4; ++r) {
            int row = rbase + w * 16 + (l >> 4) * 4 + r;
            if (row < n) {
                float v = (jj == 0) ? pj[r][0] : (jj == 1) ? pj[r][1]
                        : (jj == 2) ? pj[r][2] : pj[r][3];
                out2[(size_t)row * 4 + jj] = v + bias2[jj];
            }
        }
    }
}

// ---------------- fused edge phase: one wave/dst node -----------------------
// KV interleaved rows (512B). Chunked MLP loads; T13 defer-rescale (THR=4).
__global__ void k_edge_hf(const ushort* __restrict__ KV, const ushort* __restrict__ Q,
                          const int* __restrict__ rowp, const int* __restrict__ csrc,
                          ushort* __restrict__ H, int n, int act) {
    int wid = (int)((blockIdx.x * blockDim.x + threadIdx.x) >> 6);
    int lane = threadIdx.x & 63;
    if (wid >= n) return;
    int qb = lane >> 4;                 // edge slot within quad
    unsigned fb = (lane & 15) * 8u;     // feature base
    int e0 = rowp[wid], e1 = rowp[wid + 1];

    uint4 qr = *(const uint4*)(Q + (((unsigned)wid << 7) + fb));
    h2 q0 = __builtin_bit_cast(h2, qr.x), q1 = __builtin_bit_cast(h2, qr.y);
    h2 q2 = __builtin_bit_cast(h2, qr.z), q3 = __builtin_bit_cast(h2, qr.w);

    float m = -1e30f, denom = 0.f;
    h2 hz = {(_Float16)0.f, (_Float16)0.f};
    h2 acc0 = hz, acc1 = hz, acc2 = hz, acc3 = hz;

#define EDGE_BODY(KR, VR, VALID)                                               \
    {                                                                          \
        float sc = __builtin_amdgcn_fdot2(__builtin_bit_cast(h2, KR.x), q0,    \
                   __builtin_amdgcn_fdot2(__builtin_bit_cast(h2, KR.y), q1,    \
                   __builtin_amdgcn_fdot2(__builtin_bit_cast(h2, KR.z), q2,    \
                   __builtin_amdgcn_fdot2(__builtin_bit_cast(h2, KR.w), q3,    \
                                          0.f, false), false), false), false); \
        sc += __shfl_xor(sc, 1);                                               \
        sc += __shfl_xor(sc, 2);                                               \
        sc += __shfl_xor(sc, 4);                                               \
        if (VALID && sc > m + 4.f) {                                           \
            float ss = __expf(m - sc);                                         \
            m = sc;                                                            \
            denom *= ss;                                                       \
            h2 hs = pk2(ss, ss);                                               \
            acc0 *= hs; acc1 *= hs; acc2 *= hs; acc3 *= hs;                    \
        }                                                                      \
        float p = VALID ? __expf(sc - m) : 0.f;                                \
        denom += p;                                                            \
        h2 hp = pk2(p, p);                                                     \
        acc0 = __builtin_bit_cast(h2, VR.x) * hp + acc0;                       \
        acc1 = __builtin_bit_cast(h2, VR.y) * hp + acc1;                       \
        acc2 = __builtin_bit_cast(h2, VR.z) * hp + acc2;                       \
        acc3 = __builtin_bit_cast(h2, VR.w) * hp + acc3;                       \
    }

    for (int eb = e0; eb < e1; eb += 64) {
        int cnt = min(64, e1 - eb);
        int sl = (eb + lane < e1) ? csrc[eb + lane] : 0;
        int nq = (cnt + 3) >> 2;  // quad-iterations (<=16)
        for (int c0 = 0; c0 < nq; c0 += 4) {
            int ei0 = (c0 + 0) * 4 + qb, ei1 = (c0 + 1) * 4 + qb;
            int ei2 = (c0 + 2) * 4 + qb, ei3 = (c0 + 3) * 4 + qb;
            bool v0 = ei0 < cnt, v1 = ei1 < cnt, v2 = ei2 < cnt, v3 = ei3 < cnt;
            unsigned of0 = (((unsigned)__shfl(sl, ei0 & 63)) << 8) + fb;
            unsigned of1 = (((unsigned)__shfl(sl, ei1 & 63)) << 8) + fb;
            unsigned of2 = (((unsigned)__shfl(sl, ei2 & 63)) << 8) + fb;
            unsigned of3 = (((unsigned)__shfl(sl, ei3 & 63)) << 8) + fb;
            uint4 kr0 = *(const uint4*)(KV + of0);
            uint4 vr0 = *(const uint4*)(KV + of0 + 128);
            uint4 kr1 = *(const uint4*)(KV + of1);
            uint4 vr1 = *(const uint4*)(KV + of1 + 128);
            uint4 kr2 = *(const uint4*)(KV + of2);
            uint4 vr2 = *(const uint4*)(KV + of2 + 128);
            uint4 kr3 = *(const uint4*)(KV + of3);
            uint4 vr3 = *(const uint4*)(KV + of3 + 128);
            EDGE_BODY(kr0, vr0, v0);
            if (v1 || c0 + 4 < nq) EDGE_BODY(kr1, vr1, v1);
            if (v2 || c0 + 4 < nq) EDGE_BODY(kr2, vr2, v2);
            if (v3 || c0 + 4 < nq) EDGE_BODY(kr3, vr3, v3);
        }
    }
#undef EDGE_BODY

    // merge quarter states: lanes L, L^16, L^32, L^48 share (feats, head)
#pragma unroll
    for (int dist = 16; dist <= 32; dist <<= 1) {
        float mo = __shfl_xor(m, dist);
        float dn = __shfl_xor(denom, dist);
        unsigned w0 = __shfl_xor(__builtin_bit_cast(unsigned, acc0), dist);
        unsigned w1 = __shfl_xor(__builtin_bit_cast(unsigned, acc1), dist);
        unsigned w2 = __shfl_xor(__builtin_bit_cast(unsigned, acc2), dist);
        unsigned w3 = __shfl_xor(__builtin_bit_cast(unsigned, acc3), dist);
        float mn = fmaxf(m, mo);
        float sA = __expf(m - mn), sB = __expf(mo - mn);
        denom = denom * sA + dn * sB;
        h2 hA = pk2(sA, sA), hB = pk2(sB, sB);
        acc0 = acc0 * hA + __builtin_bit_cast(h2, w0) * hB;
        acc1 = acc1 * hA + __builtin_bit_cast(h2, w1) * hB;
        acc2 = acc2 * hA + __builtin_bit_cast(h2, w2) * hB;
        acc3 = acc3 * hA + __builtin_bit_cast(h2, w3) * hB;
        m = mn;
    }

    if (lane < 16) {
        float inv = (denom > 0.f) ? 1.f / denom : 0.f;
        ushort* hp = H + (((unsigned)wid << 7) + fb);
        uint4 hr = *(const uint4*)hp;
        h2 s0 = __builtin_bit_cast(h2, hr.x), s1 = __builtin_bit_cast(h2, hr.y);
        h2 s2 = __builtin_bit_cast(h2, hr.z), s3 = __builtin_bit_cast(h2, hr.w);
        float o0 = (float)s0.x + (float)acc0.x * inv;
        float o1 = (float)s0.y + (float)acc0.y * inv;
        float o2 = (float)s1.x + (float)acc1.x * inv;
        float o3 = (float)s1.y + (float)acc1.y * inv;
        float o4 = (float)s2.x + (float)acc2.x * inv;
        float o5 = (float)s2.y + (float)acc2.y * inv;
        float o6 = (float)s3.x + (float)acc3.x * inv;
        float o7 = (float)s3.y + (float)acc3.y * inv;
        if (act) {
            o0 = gelu_f(o0); o1 = gelu_f(o1); o2 = gelu_f(o2); o3 = gelu_f(o3);
            o4 = gelu_f(o4); o5 = gelu_f(o5); o6 = gelu_f(o6); o7 = gelu_f(o7);
        }
        uint4 o;
        o.x = __builtin_bit_cast(unsigned, pk2(o0, o1));
        o.y = __builtin_bit_cast(unsigned, pk2(o2, o3));
        o.z = __builtin_bit_cast(unsigned, pk2(o4, o5));
        o.w = __builtin_bit_cast(unsigned, pk2(o6, o7));
        *(uint4*)hp = o;
    }
}

extern "C" void kernel_launch(void* const* d_in, const int* in_sizes, int n_in,
                              void* d_out, int out_size, void* d_ws, size_t ws_size,
                              hipStream_t stream) {
    const float* x     = (const float*)d_in[0];
    const int*   src   = (const int*)d_in[1];
    const int*   dst   = (const int*)d_in[2];
    const float* fc0_w = (const float*)d_in[3];
    const float* fc0_b = (const float*)d_in[4];
    const float* Wk    = (const float*)d_in[5];
    const float* bk    = (const float*)d_in[6];
    const float* Wq    = (const float*)d_in[7];
    const float* bq    = (const float*)d_in[8];
    const float* Wv    = (const float*)d_in[9];
    const float* bv    = (const float*)d_in[10];
    const float* ws_w  = (const float*)d_in[11];
    const float* ws_b  = (const float*)d_in[12];
    const float* fc1_w = (const float*)d_in[13];
    const float* fc1_b = (const float*)d_in[14];
    const float* fc2_w = (const float*)d_in[15];
    const float* fc2_b = (const float*)d_in[16];

    int n = in_sizes[0] / 16;
    int e = in_sizes[1];

    ushort* hA  = (ushort*)d_ws;
    ushort* hB  = hA + (size_t)n * 128;
    ushort* KV  = hB + (size_t)n * 128;   // [n][256]: K | V interleaved
    ushort* Qb  = KV + (size_t)n * 256;
    ushort* Wp  = Qb + (size_t)n * 128;   // 9 * 16384 fp16
    int* deg    = (int*)(Wp + 9 * 16384);
    int* rowp   = deg + n;
    int* csrc   = rowp + n + 1;
    int* rank   = csrc + e;
    int* bsum   = rank + e;               // 128 ints scratch

    int nb = (n + 1023) / 1024;

    // CSR build
    hipMemsetAsync(deg, 0, (size_t)n * sizeof(int), stream);
    k_hist<<<(e + 255) / 256, 256, 0, stream>>>(dst, deg, rank, e);
    k_part<<<nb, 256, 0, stream>>>(deg, rowp, bsum, n);
    k_scanb<<<1, 128, 0, stream>>>(bsum, nb);
    k_add<<<nb, 256, 0, stream>>>(rowp, bsum, n, e);
    k_scatter<<<(e + 255) / 256, 256, 0, stream>>>(src, dst, rank, rowp, csrc, e);

    // pack all 9 weight matrices to fp16 frag-major
    k_pack<<<dim3(64, 9), 256, 0, stream>>>(Wk, Wq, Wv, ws_w, fc1_w, Wp);

    int gx = (n + 63) / 64;
    // layer 0 (fc0 fused): K->KV[:,0:128], Q->Qb, V->KV[:,128:256], ws->hB.
    k_gemm_proj<<<gx, 256, 0, stream>>>(nullptr, n, Wp, bk, KV, 256, bq, Qb, 128,
                                        bv, KV + 128, 256, ws_b, hB, 128,
                                        x, fc0_w, fc0_b, 1);
    k_edge_hf<<<(n + 3) / 4, 256, 0, stream>>>(KV, Qb, rowp, csrc, hB, n, 1);
    // layer 1
    k_gemm_proj<<<gx, 256, 0, stream>>>(hB, n, Wp + 4 * 16384, bk + 128, KV, 256,
                                        bq + 128, Qb, 128, bv + 128, KV + 128, 256,
                                        ws_b + 128, hA, 128,
                                        nullptr, nullptr, nullptr, 0);
    k_edge_hf<<<(n + 3) / 4, 256, 0, stream>>>(KV, Qb, rowp, csrc, hA, n, 0);

    // fc1 + gelu + fc2 fused -> d_out
    k_gemm_fc<<<gx, 256, 0, stream>>>(hA, n, Wp + 8 * 16384, fc1_b, fc2_w, fc2_b,
                                      (float*)d_out);
}